// Round 2
// baseline (562.427 us; speedup 1.0000x reference)
//
#include <hip/hip_runtime.h>
#include <stdint.h>

#define N_NODES 20000
#define N_EDGES 320000
#define EMB     256
#define D_IN    300
#define KPAD0   320   // D_IN padded to multiple of 32

typedef __attribute__((ext_vector_type(8))) short s16x8;   // 8 bf16 operand (4 VGPRs)
typedef __attribute__((ext_vector_type(4))) float f32x4;

__device__ __forceinline__ float bf2f(unsigned short u) {
    union { unsigned u; float f; } x; x.u = ((unsigned)u) << 16; return x.f;
}
__device__ __forceinline__ unsigned short f2bf(float f) {
    union { float f; unsigned u; } x; x.f = f;
    unsigned r = x.u + 0x7fffu + ((x.u >> 16) & 1u);   // RNE
    return (unsigned short)(r >> 16);
}
// split v = hi + lo (each bf16), |err| <= 2^-18 |v|
__device__ __forceinline__ void split_bf(float v, unsigned short& h, unsigned short& l) {
    h = f2bf(v);
    l = f2bf(v - bf2f(h));
}

// ---------------- CSR build ----------------

__global__ void k_init(int* deg, int* cursor, int n) {
    int i = blockIdx.x * 256 + threadIdx.x;
    if (i < n) { deg[i] = 0; cursor[i] = 0; }
}

__global__ void k_deg(const int* __restrict__ dst, int* __restrict__ deg, int e) {
    int i = blockIdx.x * 256 + threadIdx.x;
    if (i < e) atomicAdd(&deg[dst[i]], 1);
}

__global__ void k_dinv(const int* __restrict__ deg, float* __restrict__ dinv, int n) {
    int i = blockIdx.x * 256 + threadIdx.x;
    if (i < n) dinv[i] = rsqrtf((float)(deg[i] + 1));   // +1 self-loop
}

// single-block exclusive scan over deg -> row_off[0..n]
__global__ void k_scan(const int* __restrict__ deg, int* __restrict__ row_off, int n) {
    __shared__ int sums[1024];
    int tid = threadIdx.x;
    const int chunk = (n + 1023) / 1024;
    int start = tid * chunk;
    int end   = start + chunk; if (end > n) end = n; if (start > n) start = n;
    int s = 0;
    for (int i = start; i < end; ++i) s += deg[i];
    sums[tid] = s;
    __syncthreads();
    for (int off = 1; off < 1024; off <<= 1) {
        int v = (tid >= off) ? sums[tid - off] : 0;
        __syncthreads();
        sums[tid] += v;
        __syncthreads();
    }
    int excl = (tid == 0) ? 0 : sums[tid - 1];
    for (int i = start; i < end; ++i) { row_off[i] = excl; excl += deg[i]; }
    if (tid == 1023) row_off[n] = excl;
}

__global__ void k_scatter(const int* __restrict__ src, const int* __restrict__ dst,
                          const int* __restrict__ row_off, int* __restrict__ cursor,
                          const float* __restrict__ dinv,
                          int* __restrict__ csr_src, float* __restrict__ csr_norm, int e) {
    int i = blockIdx.x * 256 + threadIdx.x;
    if (i >= e) return;
    int s = src[i], d = dst[i];
    int pos = row_off[d] + atomicAdd(&cursor[d], 1);
    csr_src[pos]  = s;
    csr_norm[pos] = dinv[s] * dinv[d];
}

// W f32 [K][256] -> Wt hi/lo bf16 [256][Kpad], zero-padded beyond K
__global__ void k_wsplit(const float* __restrict__ W,
                         unsigned short* __restrict__ Wth,
                         unsigned short* __restrict__ Wtl, int K, int Kpad) {
    int idx = blockIdx.x * 256 + threadIdx.x;
    if (idx >= EMB * Kpad) return;
    int n = idx / Kpad, k = idx - n * Kpad;
    float v = (k < K) ? W[k * EMB + n] : 0.f;
    unsigned short h, l;
    split_bf(v, h, l);
    Wth[idx] = h; Wtl[idx] = l;
}

// ---------------- split-bf16 MFMA GEMM ----------------
// C[M,256] = A[M,K] @ W.  A either f32 (split in-register) or bf16 hi/lo pair.
// block = 256 threads = 4 waves; block tile 64 rows x 256 cols; wave tile 64x64.
// MFMA 16x16x32 bf16 layouts (HW-verified):
//   A: row = lane&15, k = (lane>>4)*8 + j
//   B: col = lane&15, k = (lane>>4)*8 + j   (read from W^T rows)
//   C/D: col = lane&15, row = (lane>>4)*4 + reg

__global__ __launch_bounds__(256) void k_gemm(
    const float* __restrict__ Af32,          // non-null => f32 A path
    const unsigned short* __restrict__ Ah,   // pair A path
    const unsigned short* __restrict__ Al,
    int M, int Astride, int Ksteps, int Kpad,
    const unsigned short* __restrict__ Wth,
    const unsigned short* __restrict__ Wtl,
    const float* __restrict__ bias, int relu,
    float* __restrict__ Cf,                  // non-null => f32 out
    unsigned short* __restrict__ Ch,         // else pair out
    unsigned short* __restrict__ Cl)
{
    int tid  = threadIdx.x;
    int lane = tid & 63, wave = tid >> 6;
    int quad = lane >> 4, l16 = lane & 15;
    int m_base = blockIdx.x * 64;

    f32x4 acc[4][4];
#pragma unroll
    for (int mt = 0; mt < 4; ++mt)
#pragma unroll
        for (int nt = 0; nt < 4; ++nt) acc[mt][nt] = (f32x4){0.f, 0.f, 0.f, 0.f};

    int mrow[4];
#pragma unroll
    for (int mt = 0; mt < 4; ++mt) {
        int m = m_base + mt * 16 + l16;
        if (m >= M) m = M - 1;               // clamp; OOB rows never stored
        mrow[mt] = m;
    }
    const unsigned short* bh_row[4];
    const unsigned short* bl_row[4];
#pragma unroll
    for (int nt = 0; nt < 4; ++nt) {
        int nn = wave * 64 + nt * 16 + l16;
        bh_row[nt] = Wth + (size_t)nn * Kpad;
        bl_row[nt] = Wtl + (size_t)nn * Kpad;
    }

    for (int ks = 0; ks < Ksteps; ++ks) {
        int k0 = ks * 32 + quad * 8;
        s16x8 ah[4], al[4], bh[4], bl[4];
#pragma unroll
        for (int nt = 0; nt < 4; ++nt) {
            bh[nt] = *(const s16x8*)(bh_row[nt] + k0);
            bl[nt] = *(const s16x8*)(bl_row[nt] + k0);
        }
        if (Af32) {
#pragma unroll
            for (int mt = 0; mt < 4; ++mt) {
                const float* arow = Af32 + (size_t)mrow[mt] * Astride;
                float fv[8];
                bool last = (mrow[mt] == M - 1) && (k0 + 8 > Astride);
                if (last) {
#pragma unroll
                    for (int j = 0; j < 8; ++j) {
                        int kk = k0 + j;
                        fv[j] = (kk < Astride) ? arow[kk] : 0.f;
                    }
                } else {
                    float4 f0 = *(const float4*)(arow + k0);
                    float4 f1 = *(const float4*)(arow + k0 + 4);
                    fv[0] = f0.x; fv[1] = f0.y; fv[2] = f0.z; fv[3] = f0.w;
                    fv[4] = f1.x; fv[5] = f1.y; fv[6] = f1.z; fv[7] = f1.w;
                }
                s16x8 hv, lv;
#pragma unroll
                for (int j = 0; j < 8; ++j) {
                    unsigned short h, l;
                    split_bf(fv[j], h, l);
                    hv[j] = (short)h; lv[j] = (short)l;
                }
                ah[mt] = hv; al[mt] = lv;
            }
        } else {
#pragma unroll
            for (int mt = 0; mt < 4; ++mt) {
                const unsigned short* ar_h = Ah + (size_t)mrow[mt] * Astride;
                const unsigned short* ar_l = Al + (size_t)mrow[mt] * Astride;
                ah[mt] = *(const s16x8*)(ar_h + k0);
                al[mt] = *(const s16x8*)(ar_l + k0);
            }
        }
#pragma unroll
        for (int mt = 0; mt < 4; ++mt)
#pragma unroll
            for (int nt = 0; nt < 4; ++nt) {
                acc[mt][nt] = __builtin_amdgcn_mfma_f32_16x16x32_bf16(
                    ah[mt], bh[nt], acc[mt][nt], 0, 0, 0);
                acc[mt][nt] = __builtin_amdgcn_mfma_f32_16x16x32_bf16(
                    ah[mt], bl[nt], acc[mt][nt], 0, 0, 0);
                acc[mt][nt] = __builtin_amdgcn_mfma_f32_16x16x32_bf16(
                    al[mt], bh[nt], acc[mt][nt], 0, 0, 0);
            }
    }

#pragma unroll
    for (int mt = 0; mt < 4; ++mt) {
        int rbase = m_base + mt * 16 + quad * 4;
#pragma unroll
        for (int r = 0; r < 4; ++r) {
            int row = rbase + r;
            if (row >= M) continue;
#pragma unroll
            for (int nt = 0; nt < 4; ++nt) {
                int col = wave * 64 + nt * 16 + l16;
                float v = acc[mt][nt][r];
                if (bias) v += bias[col];
                if (relu) v = fmaxf(v, 0.f);
                size_t o = (size_t)row * EMB + col;
                if (Cf) {
                    Cf[o] = v;
                } else {
                    unsigned short h, l;
                    split_bf(v, h, l);
                    Ch[o] = h; Cl[o] = l;
                }
            }
        }
    }
}

// ---------------- Aggregation ----------------
// out[i] = bias + dinv[i]^2*h[i] + sum_j norm_j*h[src_j]; optional relu; pair output.
// one wave per node, lane owns 4 consecutive dims.

__global__ __launch_bounds__(256) void k_agg(
    const float* __restrict__ h,
    const int* __restrict__ row_off, const int* __restrict__ csr_src,
    const float* __restrict__ csr_norm, const float* __restrict__ dinv,
    const float* __restrict__ bias, int relu,
    unsigned short* __restrict__ Oh, unsigned short* __restrict__ Ol)
{
    int node = blockIdx.x * 4 + (threadIdx.x >> 6);
    if (node >= N_NODES) return;
    int lane = threadIdx.x & 63;
    int d0 = lane * 4;

    float dv = dinv[node];
    float wself = dv * dv;
    float4 sv = *(const float4*)(h + (size_t)node * EMB + d0);
    float4 bv = *(const float4*)(bias + d0);
    float a0 = bv.x + wself * sv.x;
    float a1 = bv.y + wself * sv.y;
    float a2 = bv.z + wself * sv.z;
    float a3 = bv.w + wself * sv.w;

    int jbeg = row_off[node], jend = row_off[node + 1];
    for (int j = jbeg; j < jend; ++j) {
        int   s = csr_src[j];
        float w = csr_norm[j];
        float4 v = *(const float4*)(h + (size_t)s * EMB + d0);
        a0 += w * v.x;
        a1 += w * v.y;
        a2 += w * v.z;
        a3 += w * v.w;
    }
    if (relu) {
        a0 = fmaxf(a0, 0.f); a1 = fmaxf(a1, 0.f);
        a2 = fmaxf(a2, 0.f); a3 = fmaxf(a3, 0.f);
    }
    size_t o = (size_t)node * EMB + d0;
    unsigned short hh, ll;
    split_bf(a0, hh, ll); Oh[o + 0] = hh; Ol[o + 0] = ll;
    split_bf(a1, hh, ll); Oh[o + 1] = hh; Ol[o + 1] = ll;
    split_bf(a2, hh, ll); Oh[o + 2] = hh; Ol[o + 2] = ll;
    split_bf(a3, hh, ll); Oh[o + 3] = hh; Ol[o + 3] = ll;
}

// ---------------- launch ----------------

extern "C" void kernel_launch(void* const* d_in, const int* in_sizes, int n_in,
                              void* d_out, int out_size, void* d_ws, size_t ws_size,
                              hipStream_t stream) {
    const float* x  = (const float*)d_in[0];
    const int*   ei = (const int*)d_in[1];
    const int* src = ei;
    const int* dst = ei + N_EDGES;

    const float* w[6] = {
        (const float*)d_in[2], (const float*)d_in[4], (const float*)d_in[6],
        (const float*)d_in[8], (const float*)d_in[10], (const float*)d_in[12] };
    const float* b[6] = {
        (const float*)d_in[3], (const float*)d_in[5], (const float*)d_in[7],
        (const float*)d_in[9], (const float*)d_in[11], (const float*)d_in[13] };

    char* wsp = (char*)d_ws;
    auto alloc = [&](size_t bytes) {
        char* p = wsp; wsp += (bytes + 255) & ~(size_t)255; return p;
    };
    int*   deg      = (int*)alloc(N_NODES * 4);
    int*   cursor   = (int*)alloc(N_NODES * 4);
    int*   row_off  = (int*)alloc((N_NODES + 1) * 4);
    int*   csr_src  = (int*)alloc(N_EDGES * 4);
    float* csr_norm = (float*)alloc(N_EDGES * 4);
    float* dinv     = (float*)alloc(N_NODES * 4);
    unsigned short* wth[6];
    unsigned short* wtl[6];
    wth[0] = (unsigned short*)alloc(EMB * KPAD0 * 2);
    wtl[0] = (unsigned short*)alloc(EMB * KPAD0 * 2);
    for (int i = 1; i < 6; ++i) {
        wth[i] = (unsigned short*)alloc(EMB * EMB * 2);
        wtl[i] = (unsigned short*)alloc(EMB * EMB * 2);
    }
    unsigned short* HPh = (unsigned short*)alloc((size_t)N_NODES * EMB * 2);
    unsigned short* HPl = (unsigned short*)alloc((size_t)N_NODES * EMB * 2);
    float* F = (float*)d_out;   // f32 scratch == final output buffer

    const int NB_N = (N_NODES + 255) / 256;   // 79
    const int NB_E = (N_EDGES + 255) / 256;   // 1250
    const int MB   = (N_NODES + 63) / 64;     // 313

    // CSR build
    k_init<<<NB_N, 256, 0, stream>>>(deg, cursor, N_NODES);
    k_deg<<<NB_E, 256, 0, stream>>>(dst, deg, N_EDGES);
    k_dinv<<<NB_N, 256, 0, stream>>>(deg, dinv, N_NODES);
    k_scan<<<1, 1024, 0, stream>>>(deg, row_off, N_NODES);
    k_scatter<<<NB_E, 256, 0, stream>>>(src, dst, row_off, cursor, dinv,
                                        csr_src, csr_norm, N_EDGES);

    // weight transpose + split
    k_wsplit<<<(EMB * KPAD0 + 255) / 256, 256, 0, stream>>>(w[0], wth[0], wtl[0], D_IN, KPAD0);
    for (int i = 1; i < 6; ++i)
        k_wsplit<<<(EMB * EMB) / 256, 256, 0, stream>>>(w[i], wth[i], wtl[i], EMB, EMB);

    // conv0: x @ W0 -> F ; aggregate(+b0, relu) -> HP pair
    k_gemm<<<MB, 256, 0, stream>>>(x, nullptr, nullptr, N_NODES, D_IN, KPAD0 / 32, KPAD0,
                                   wth[0], wtl[0], nullptr, 0, F, nullptr, nullptr);
    k_agg<<<N_NODES / 4, 256, 0, stream>>>(F, row_off, csr_src, csr_norm, dinv,
                                           b[0], 1, HPh, HPl);
    // conv1
    k_gemm<<<MB, 256, 0, stream>>>(nullptr, HPh, HPl, N_NODES, EMB, EMB / 32, EMB,
                                   wth[1], wtl[1], nullptr, 0, F, nullptr, nullptr);
    k_agg<<<N_NODES / 4, 256, 0, stream>>>(F, row_off, csr_src, csr_norm, dinv,
                                           b[1], 1, HPh, HPl);
    // conv2 (no relu after agg)
    k_gemm<<<MB, 256, 0, stream>>>(nullptr, HPh, HPl, N_NODES, EMB, EMB / 32, EMB,
                                   wth[2], wtl[2], nullptr, 0, F, nullptr, nullptr);
    k_agg<<<N_NODES / 4, 256, 0, stream>>>(F, row_off, csr_src, csr_norm, dinv,
                                           b[2], 0, HPh, HPl);
    // mlp1, mlp2: pair in/out in-place (block-row ownership makes this safe)
    k_gemm<<<MB, 256, 0, stream>>>(nullptr, HPh, HPl, N_NODES, EMB, EMB / 32, EMB,
                                   wth[3], wtl[3], b[3], 1, nullptr, HPh, HPl);
    k_gemm<<<MB, 256, 0, stream>>>(nullptr, HPh, HPl, N_NODES, EMB, EMB / 32, EMB,
                                   wth[4], wtl[4], b[4], 1, nullptr, HPh, HPl);
    // mlp3 -> d_out f32
    k_gemm<<<MB, 256, 0, stream>>>(nullptr, HPh, HPl, N_NODES, EMB, EMB / 32, EMB,
                                   wth[5], wtl[5], b[5], 0, F, nullptr, nullptr);
}